// Round 17
// baseline (526.697 us; speedup 1.0000x reference)
//
#include <hip/hip_runtime.h>

#define NB 8192
#define NT 50

typedef _Float16 half8 __attribute__((ext_vector_type(8)));
typedef float f32x4 __attribute__((ext_vector_type(4)));

__device__ __forceinline__ float leaky(float x) { return x > 0.0f ? x : 0.3f * x; }
__device__ __forceinline__ float frcp(float x) { return __builtin_amdgcn_rcpf(x); }

#define LVL_SCALE   4096.0f
#define LVL_UNSCALE 0.000244140625f   // 2^-12

extern "C" __global__ __launch_bounds__(256, 4)
void idm_rollout_kernel(const float* __restrict__ idm_params,
                        const float* __restrict__ proj_latent,
                        const float* __restrict__ enc_h,
                        const float* __restrict__ idm_s,
                        const float* __restrict__ merger_cs,
                        const float* __restrict__ scaler_mean,
                        const float* __restrict__ scaler_var,
                        const float* __restrict__ W1,
                        const float* __restrict__ b1,
                        const float* __restrict__ W2,
                        const float* __restrict__ b2,
                        const float* __restrict__ Wf,
                        const float* __restrict__ bfp,
                        const float* __restrict__ Wm,
                        const float* __restrict__ bmp,
                        float* __restrict__ out)
{
    // h1 2-level fp16 fragments: [kchunk][lvl][lane][e]  (identity slot map)
    __shared__ __align__(16) _Float16 s_a[4][2][64][8];    // 8 KB
    // dynamic W1 rows 256..266 (env rows pre-scaled by inv_std)
    __shared__ __align__(16) float s_w1d[11][128];         // 5.5 KB
    // head partials: [col-elem][2*w + {f,m}], padded row stride 12
    __shared__ __align__(16) float s_part[16][12];         // 0.75 KB

    const int tid = threadIdx.x;       // 0..255
    const int w   = tid >> 6;          // wave 0..3
    const int l   = tid & 63;
    const int lm  = l & 15;            // MFMA col index; elem = lm & 7 (cols 8..15 duplicate)
    const int lq  = l >> 4;
    const int b0  = blockIdx.x * 8;    // 8 elems/block -> grid 1024 = 4 blocks/CU
    const int bm  = b0 + (lm & 7);     // this lane's batch element
    const int c0  = w * 32 + lq * 8;   // this lane's 8 layer-1 columns (= consumer slice kc=w)

    // ---- stage dynamic W1 rows; env rows scaled by inv_std ----
    for (int idx = tid; idx < 11 * 128; idx += 256) {
        const int r = idx >> 7, c = idx & 127;
        float wv_ = W1[(256 + r) * 128 + c];
        if (r < 8) wv_ *= 1.0f / sqrtf(scaler_var[r]);
        s_w1d[r][c] = wv_;
    }

    // ---- W2^T A-frags for 2 jtiles, 2-level fp16 in registers ----
    // level-1 scaled by 2^12 (stays in fp16 normal range; undone in epilogue)
    half8 W2T0[2][4], W2T1[2][4];
    #pragma unroll
    for (int jt = 0; jt < 2; ++jt) {
        const int jtg = 2 * w + jt;
        #pragma unroll
        for (int kc = 0; kc < 4; ++kc) {
            #pragma unroll
            for (int e = 0; e < 8; ++e) {
                const int k = kc * 32 + lq * 8 + e;
                const float v = W2[k * 128 + jtg * 16 + lm];
                const _Float16 q0 = (_Float16)v;
                const float r1 = (v - (float)q0) * LVL_SCALE;   // exact diff, exact scale
                W2T0[jt][kc][e] = q0;
                W2T1[jt][kc][e] = (_Float16)r1;
            }
        }
    }

    // ---- head constants for this lane's D cols (2 jtiles) ----
    f32x4 b2r[2], wfr[2], wmr[2];
    #pragma unroll
    for (int jt = 0; jt < 2; ++jt) {
        const int cb = (2 * w + jt) * 16 + lq * 4;
        b2r[jt] = *(const f32x4*)&b2[cb];
        wfr[jt] = *(const f32x4*)&Wf[cb];
        wmr[jt] = *(const f32x4*)&Wm[cb];
    }
    const float bfv = bfp[0];
    const float bmv = bmp[0];

    __syncthreads();   // s_w1d staged (needed by hpre fold below)

    // ---- hpre for (elem bm, cols c0..c0+7) ----
    f32x4 hpA = *(const f32x4*)&b1[c0];
    f32x4 hpB = *(const f32x4*)&b1[c0 + 4];
    {
        const float* xl0 = proj_latent + (size_t)bm * 128;
        const float* xl1 = enc_h + (size_t)bm * 128;
        #pragma unroll 2
        for (int r0 = 0; r0 < 128; r0 += 4) {
            const f32x4 x = *(const f32x4*)&xl0[r0];
            #pragma unroll
            for (int j = 0; j < 4; ++j) {
                hpA += x[j] * *(const f32x4*)&W1[(r0 + j) * 128 + c0];
                hpB += x[j] * *(const f32x4*)&W1[(r0 + j) * 128 + c0 + 4];
            }
        }
        #pragma unroll 2
        for (int r0 = 0; r0 < 128; r0 += 4) {
            const f32x4 x = *(const f32x4*)&xl1[r0];
            #pragma unroll
            for (int j = 0; j < 4; ++j) {
                hpA += x[j] * *(const f32x4*)&W1[(128 + r0 + j) * 128 + c0];
                hpB += x[j] * *(const f32x4*)&W1[(128 + r0 + j) * 128 + c0 + 4];
            }
        }
        #pragma unroll
        for (int rr = 0; rr < 8; ++rr) {   // fold -(mean*inv_std)@W1env (s_w1d pre-scaled)
            const float c = scaler_mean[rr];
            hpA -= c * *(const f32x4*)&s_w1d[rr][c0];
            hpB -= c * *(const f32x4*)&s_w1d[rr][c0 + 4];
        }
    }

    // ---- per-lane dynamics state for elem bm (redundant across lanes) ----
    float ego_v_r, ego_a_r, ego_x_r, disp_r;
    float ef_dv_r, ef_dx_r, em_dv_r, em_dx_r;
    float c_fa, c_fv, c_m0, c_m1, c_m2;
    {
        const float* sr = idm_s + (size_t)bm * 714;     // 51*14
        const float* mr = merger_cs + (size_t)bm * 150;
        ego_v_r = sr[0]; ego_a_r = sr[11]; ego_x_r = sr[3]; disp_r = 0.0f;
        const float fv0 = sr[1], mv0 = sr[2], fx0 = sr[4], mx0 = sr[5];
        c_fa = sr[12];
        const float me0 = sr[13];
        c_fv = fv0;
        ef_dx_r = fx0 - ego_x_r;
        em_dx_r = (mx0 - ego_x_r) * me0 + (1.0f - me0) * 100.0f;
        ef_dv_r = ego_v_r - fv0;
        em_dv_r = (ego_v_r - mv0) * me0;
        c_m0 = mr[0]; c_m1 = mr[1]; c_m2 = mr[2];
    }
    const float ptg    = idm_params[bm * 5 + 1];
    const float pjam   = idm_params[bm * 5 + 2];
    const float pamax  = idm_params[bm * 5 + 3];
    const float pinv_v0 = 1.0f / idm_params[bm * 5 + 0];
    const float pinv_gd = 1.0f / (2.0f * sqrtf(pamax * idm_params[bm * 5 + 4]));

    float* out_disp = out;
    float* out_act  = out + NB * 51;
    float* out_fat  = out + NB * (51 + 50);
    float* out_mat  = out + NB * (51 + 100);
    if (tid < 8) out_disp[bm * 51] = 0.0f;

    for (int t = 0; t < NT; ++t) {
        // ---- prefetch next-step exogenous scalars (own elem) ----
        float nf_fv = 0, nf_mv = 0, nf_fx = 0, nf_mx = 0, nf_fa = 0, nf_me = 0;
        float nf_m0 = 0, nf_m1 = 0, nf_m2 = 0;
        if (t + 1 < NT) {
            const float* sp = idm_s + (size_t)bm * 714 + (t + 1) * 14;
            nf_fv = sp[1]; nf_mv = sp[2]; nf_fx = sp[4]; nf_mx = sp[5];
            nf_fa = sp[12]; nf_me = sp[13];
            const float* mp = merger_cs + (size_t)bm * 150 + (t + 1) * 3;
            nf_m0 = mp[0]; nf_m1 = mp[1]; nf_m2 = mp[2];
        }

        // ---- phase A: layer-1 via VALU (8 cols, 11 dyn rows from LDS) ----
        float ev[11];
        ev[0] = ego_a_r; ev[1] = c_fa;    ev[2] = ego_v_r; ev[3] = c_fv;
        ev[4] = ef_dv_r; ev[5] = ef_dx_r; ev[6] = em_dv_r; ev[7] = em_dx_r;
        ev[8] = c_m0;    ev[9] = c_m1;    ev[10] = c_m2;
        f32x4 hqA = hpA, hqB = hpB;
        #pragma unroll
        for (int r = 0; r < 11; ++r) {
            hqA += ev[r] * *(const f32x4*)&s_w1d[r][c0];
            hqB += ev[r] * *(const f32x4*)&s_w1d[r][c0 + 4];
        }
        float h[8];
        h[0] = leaky(hqA.x); h[1] = leaky(hqA.y); h[2] = leaky(hqA.z); h[3] = leaky(hqA.w);
        h[4] = leaky(hqB.x); h[5] = leaky(hqB.y); h[6] = leaky(hqB.z); h[7] = leaky(hqB.w);

        // 2-level fp16 split (RN); level-1 pre-scaled by 2^12 before conversion
        half8 A0, A1;
        #pragma unroll
        for (int e = 0; e < 8; ++e) {
            const float v = h[e];
            const _Float16 q0 = (_Float16)v;
            A0[e] = q0;
            A1[e] = (_Float16)((v - (float)q0) * LVL_SCALE);
        }
        *(half8*)&s_a[w][0][l][0] = A0;
        *(half8*)&s_a[w][1][l][0] = A1;

        __syncthreads();   // B1: h1 fragments visible (4-wave domain)

        // ---- phase B: layer-2 via swapped fp16 MFMA, 3 terms, 2 jtiles ----
        f32x4 aA[2], aB[2], aC[2];
        #pragma unroll
        for (int jt = 0; jt < 2; ++jt) {
            aA[jt] = f32x4{0,0,0,0}; aB[jt] = f32x4{0,0,0,0}; aC[jt] = f32x4{0,0,0,0};
        }
        #pragma unroll
        for (int kc = 0; kc < 4; ++kc) {
            const half8 x0 = *(const half8*)&s_a[kc][0][l][0];
            const half8 x1 = *(const half8*)&s_a[kc][1][l][0];
            #pragma unroll
            for (int jt = 0; jt < 2; ++jt) {
                aA[jt] = __builtin_amdgcn_mfma_f32_16x16x32_f16(W2T0[jt][kc], x0, aA[jt], 0, 0, 0);
                aB[jt] = __builtin_amdgcn_mfma_f32_16x16x32_f16(W2T1[jt][kc], x0, aB[jt], 0, 0, 0);
                aC[jt] = __builtin_amdgcn_mfma_f32_16x16x32_f16(W2T0[jt][kc], x1, aC[jt], 0, 0, 0);
            }
        }
        // heads: h2 = aA + (aB + aC)*2^-12 + b2  (undo level-1 scaling)
        float fsc = 0.0f, msc = 0.0f;
        #pragma unroll
        for (int jt = 0; jt < 2; ++jt) {
            #pragma unroll
            for (int r = 0; r < 4; ++r) {
                const float h2 = leaky(aA[jt][r] + (aB[jt][r] + aC[jt][r]) * LVL_UNSCALE
                                       + b2r[jt][r]);
                fsc += h2 * wfr[jt][r];
                msc += h2 * wmr[jt][r];
            }
        }
        // reduce over lq (xor16/32)
        fsc += __shfl_xor(fsc, 16); fsc += __shfl_xor(fsc, 32);
        msc += __shfl_xor(msc, 16); msc += __shfl_xor(msc, 32);
        if (l < 16) *(float2*)&s_part[lm][w * 2] = make_float2(fsc, msc);

        __syncthreads();   // B2: head partials visible

        // ---- phase C: dynamics, redundant on all lanes (own elem bm) ----
        {
            // s_part row lm holds the scores of elem (lm & 7) -- duplicate rows agree
            const f32x4 p0 = *(const f32x4*)&s_part[lm][0];
            const f32x4 p1 = *(const f32x4*)&s_part[lm][4];
            const float fsum = bfv + p0.x + p0.z + p1.x + p1.z;
            const float msum = bmv + p0.y + p0.w + p1.y + p1.w;

            const float f_sc = fminf(fmaxf(fsum, -20.0f), 20.0f);
            const float m_sc = fminf(fmaxf(msum, -20.0f), 20.0f);
            const float dsc = 5.0f * (f_sc - m_sc);
            const float ex  = __expf(-fabsf(dsc));
            const float inv = frcp(1.0f + ex);
            const float fatt = (dsc >= 0.0f) ? inv : ex * inv;
            const float matt = 1.0f - fatt;

            // shared IDM terms
            const float rr_ = ego_v_r * pinv_v0;
            const float rr2 = rr_ * rr_;
            const float base = pamax * (1.0f - rr2 * rr2);
            // follower branch
            const float dxf = fminf(fmaxf(ef_dx_r, 0.1f), 500.0f);
            const float gapf = ptg * ego_v_r + ego_v_r * ef_dv_r * pinv_gd;
            const float dgf = pjam + fmaxf(gapf, 0.0f);
            const float qf = dgf * frcp(dxf);
            const float efa = fminf(fmaxf(base - pamax * qf * qf, -6.0f), 6.0f);
            // merger branch
            const float dxm = fminf(fmaxf(em_dx_r, 0.1f), 500.0f);
            const float gapm = ptg * ego_v_r + ego_v_r * em_dv_r * pinv_gd;
            const float dgm = pjam + fmaxf(gapm, 0.0f);
            const float qm = dgm * frcp(dxm);
            const float ema = fminf(fmaxf(base - pamax * qm * qm, -6.0f), 6.0f);

            const float a2n = fatt * efa + matt * ema;

            const float delta = ego_v_r * 0.1f + 0.005f * a2n;
            disp_r  += delta;
            ego_x_r += delta;
            ego_v_r += a2n * 0.1f;
            ego_a_r  = a2n;

            if (tid < 8) {
                out_disp[bm * 51 + t + 1] = disp_r;
                out_act [bm * 50 + t]     = a2n;
                out_fat [bm * 50 + t]     = fatt;
                out_mat [bm * 50 + t]     = matt;
            }

            if (t + 1 < NT) {
                ef_dx_r = nf_fx - ego_x_r;
                em_dx_r = (nf_mx - ego_x_r) * nf_me + (1.0f - nf_me) * 100.0f;
                ef_dv_r = ego_v_r - nf_fv;
                em_dv_r = (ego_v_r - nf_mv) * nf_me;
                c_fa = nf_fa; c_fv = nf_fv;
                c_m0 = nf_m0; c_m1 = nf_m1; c_m2 = nf_m2;
            }
        }
        // no 3rd barrier: s_a rewrite (t+1) is fenced by B2;
        // s_part rewrite (t+1) is fenced by B1(t+1).
    }
}

extern "C" void kernel_launch(void* const* d_in, const int* in_sizes, int n_in,
                              void* d_out, int out_size, void* d_ws, size_t ws_size,
                              hipStream_t stream) {
    (void)in_sizes; (void)n_in; (void)d_ws; (void)ws_size; (void)out_size;
    const float* idm_params  = (const float*)d_in[0];
    const float* proj_latent = (const float*)d_in[1];
    const float* enc_h       = (const float*)d_in[2];
    const float* idm_s       = (const float*)d_in[3];
    const float* merger_cs   = (const float*)d_in[4];
    const float* scaler_mean = (const float*)d_in[5];
    const float* scaler_var  = (const float*)d_in[6];
    const float* W1          = (const float*)d_in[7];
    const float* b1          = (const float*)d_in[8];
    const float* W2          = (const float*)d_in[9];
    const float* b2          = (const float*)d_in[10];
    const float* Wf          = (const float*)d_in[11];
    const float* bfp         = (const float*)d_in[12];
    const float* Wm          = (const float*)d_in[13];
    const float* bmp         = (const float*)d_in[14];

    idm_rollout_kernel<<<dim3(NB / 8), dim3(256), 0, stream>>>(
        idm_params, proj_latent, enc_h, idm_s, merger_cs,
        scaler_mean, scaler_var, W1, b1, W2, b2, Wf, bfp, Wm, bmp,
        (float*)d_out);
}

// Round 18
// 156.723 us; speedup vs baseline: 3.3607x; 3.3607x over previous
//
#include <hip/hip_runtime.h>

#define NB 8192
#define NT 50

typedef _Float16 half8 __attribute__((ext_vector_type(8)));
typedef float f32x4 __attribute__((ext_vector_type(4)));

__device__ __forceinline__ float leaky(float x) { return x > 0.0f ? x : 0.3f * x; }
__device__ __forceinline__ float frcp(float x) { return __builtin_amdgcn_rcpf(x); }

#define LVL_SCALE   4096.0f
#define LVL_UNSCALE 0.000244140625f   // 2^-12

extern "C" __global__ __launch_bounds__(256, 2)
void idm_rollout_kernel(const float* __restrict__ idm_params,
                        const float* __restrict__ proj_latent,
                        const float* __restrict__ enc_h,
                        const float* __restrict__ idm_s,
                        const float* __restrict__ merger_cs,
                        const float* __restrict__ scaler_mean,
                        const float* __restrict__ scaler_var,
                        const float* __restrict__ W1,
                        const float* __restrict__ b1,
                        const float* __restrict__ W2,
                        const float* __restrict__ b2,
                        const float* __restrict__ Wf,
                        const float* __restrict__ bfp,
                        const float* __restrict__ Wm,
                        const float* __restrict__ bmp,
                        float* __restrict__ out)
{
    // h1 2-level fp16 fragments: [kchunk][lvl][lane][e]  (identity slot map)
    __shared__ __align__(16) _Float16 s_a[4][2][64][8];    // 8 KB
    // head partials: [elem][2*w + {f,m}], padded row stride 12
    __shared__ __align__(16) float s_part[16][12];         // 0.75 KB

    const int tid = threadIdx.x;       // 0..255
    const int w   = tid >> 6;          // wave 0..3
    const int l   = tid & 63;
    const int lm  = l & 15;            // this lane's batch element (within block)
    const int lq  = l >> 4;
    const int b0  = blockIdx.x * 16;
    const int bm  = b0 + lm;
    const int c0  = w * 32 + lq * 8;   // this lane's 8 layer-1 columns (= consumer slice kc=w)

    // ---- dynamic W1 rows 256..266 at this lane's 8 columns, in REGISTERS ----
    // env rows (r<8) pre-scaled by inv_std. 22 f32x4 = 88 VGPR, loop-invariant.
    f32x4 w1dA[11], w1dB[11];
    #pragma unroll
    for (int r = 0; r < 11; ++r) {
        f32x4 a = *(const f32x4*)&W1[(256 + r) * 128 + c0];
        f32x4 b = *(const f32x4*)&W1[(256 + r) * 128 + c0 + 4];
        if (r < 8) {
            const float is = 1.0f / sqrtf(scaler_var[r]);
            a *= is; b *= is;
        }
        w1dA[r] = a; w1dB[r] = b;
    }

    // ---- W2^T A-frags for 2 jtiles, 2-level fp16 in registers (64 VGPR) ----
    // level-1 scaled by 2^12 (stays in fp16 normal range; undone in epilogue)
    half8 W2T0[2][4], W2T1[2][4];
    #pragma unroll
    for (int jt = 0; jt < 2; ++jt) {
        const int jtg = 2 * w + jt;
        #pragma unroll
        for (int kc = 0; kc < 4; ++kc) {
            #pragma unroll
            for (int e = 0; e < 8; ++e) {
                const int k = kc * 32 + lq * 8 + e;
                const float v = W2[k * 128 + jtg * 16 + lm];
                const _Float16 q0 = (_Float16)v;
                const float r1 = (v - (float)q0) * LVL_SCALE;   // exact diff, exact scale
                W2T0[jt][kc][e] = q0;
                W2T1[jt][kc][e] = (_Float16)r1;
            }
        }
    }

    // ---- head constants for this lane's D cols (2 jtiles) ----
    f32x4 b2r[2], wfr[2], wmr[2];
    #pragma unroll
    for (int jt = 0; jt < 2; ++jt) {
        const int cb = (2 * w + jt) * 16 + lq * 4;
        b2r[jt] = *(const f32x4*)&b2[cb];
        wfr[jt] = *(const f32x4*)&Wf[cb];
        wmr[jt] = *(const f32x4*)&Wm[cb];
    }
    const float bfv = bfp[0];
    const float bmv = bmp[0];

    // ---- hpre for (elem lm, cols c0..c0+7) ----
    f32x4 hpA = *(const f32x4*)&b1[c0];
    f32x4 hpB = *(const f32x4*)&b1[c0 + 4];
    {
        const float* xl0 = proj_latent + (size_t)bm * 128;
        const float* xl1 = enc_h + (size_t)bm * 128;
        #pragma unroll 2
        for (int r0 = 0; r0 < 128; r0 += 4) {
            const f32x4 x = *(const f32x4*)&xl0[r0];
            #pragma unroll
            for (int j = 0; j < 4; ++j) {
                hpA += x[j] * *(const f32x4*)&W1[(r0 + j) * 128 + c0];
                hpB += x[j] * *(const f32x4*)&W1[(r0 + j) * 128 + c0 + 4];
            }
        }
        #pragma unroll 2
        for (int r0 = 0; r0 < 128; r0 += 4) {
            const f32x4 x = *(const f32x4*)&xl1[r0];
            #pragma unroll
            for (int j = 0; j < 4; ++j) {
                hpA += x[j] * *(const f32x4*)&W1[(128 + r0 + j) * 128 + c0];
                hpB += x[j] * *(const f32x4*)&W1[(128 + r0 + j) * 128 + c0 + 4];
            }
        }
        #pragma unroll
        for (int rr = 0; rr < 8; ++rr) {   // fold -(mean*inv_std)@W1env (w1d pre-scaled)
            const float c = scaler_mean[rr];
            hpA -= c * w1dA[rr];
            hpB -= c * w1dB[rr];
        }
    }

    // ---- per-lane dynamics state for elem bm (redundant x16) ----
    float ego_v_r, ego_a_r, ego_x_r, disp_r;
    float ef_dv_r, ef_dx_r, em_dv_r, em_dx_r;
    float c_fa, c_fv, c_m0, c_m1, c_m2;
    {
        const float* sr = idm_s + (size_t)bm * 714;     // 51*14
        const float* mr = merger_cs + (size_t)bm * 150;
        ego_v_r = sr[0]; ego_a_r = sr[11]; ego_x_r = sr[3]; disp_r = 0.0f;
        const float fv0 = sr[1], mv0 = sr[2], fx0 = sr[4], mx0 = sr[5];
        c_fa = sr[12];
        const float me0 = sr[13];
        c_fv = fv0;
        ef_dx_r = fx0 - ego_x_r;
        em_dx_r = (mx0 - ego_x_r) * me0 + (1.0f - me0) * 100.0f;
        ef_dv_r = ego_v_r - fv0;
        em_dv_r = (ego_v_r - mv0) * me0;
        c_m0 = mr[0]; c_m1 = mr[1]; c_m2 = mr[2];
    }
    const float ptg    = idm_params[bm * 5 + 1];
    const float pjam   = idm_params[bm * 5 + 2];
    const float pamax  = idm_params[bm * 5 + 3];
    const float pinv_v0 = 1.0f / idm_params[bm * 5 + 0];
    const float pinv_gd = 1.0f / (2.0f * sqrtf(pamax * idm_params[bm * 5 + 4]));

    float* out_disp = out;
    float* out_act  = out + NB * 51;
    float* out_fat  = out + NB * (51 + 50);
    float* out_mat  = out + NB * (51 + 100);
    if (tid < 16) out_disp[bm * 51] = 0.0f;

    for (int t = 0; t < NT; ++t) {
        // ---- prefetch next-step exogenous scalars (own elem) ----
        float nf_fv = 0, nf_mv = 0, nf_fx = 0, nf_mx = 0, nf_fa = 0, nf_me = 0;
        float nf_m0 = 0, nf_m1 = 0, nf_m2 = 0;
        if (t + 1 < NT) {
            const float* sp = idm_s + (size_t)bm * 714 + (t + 1) * 14;
            nf_fv = sp[1]; nf_mv = sp[2]; nf_fx = sp[4]; nf_mx = sp[5];
            nf_fa = sp[12]; nf_me = sp[13];
            const float* mp = merger_cs + (size_t)bm * 150 + (t + 1) * 3;
            nf_m0 = mp[0]; nf_m1 = mp[1]; nf_m2 = mp[2];
        }

        // ---- phase A: layer-1, pure registers ----
        float ev[11];
        ev[0] = ego_a_r; ev[1] = c_fa;    ev[2] = ego_v_r; ev[3] = c_fv;
        ev[4] = ef_dv_r; ev[5] = ef_dx_r; ev[6] = em_dv_r; ev[7] = em_dx_r;
        ev[8] = c_m0;    ev[9] = c_m1;    ev[10] = c_m2;
        f32x4 hqA = hpA, hqB = hpB;
        #pragma unroll
        for (int r = 0; r < 11; ++r) {
            hqA += ev[r] * w1dA[r];
            hqB += ev[r] * w1dB[r];
        }
        float h[8];
        h[0] = leaky(hqA.x); h[1] = leaky(hqA.y); h[2] = leaky(hqA.z); h[3] = leaky(hqA.w);
        h[4] = leaky(hqB.x); h[5] = leaky(hqB.y); h[6] = leaky(hqB.z); h[7] = leaky(hqB.w);

        // 2-level fp16 split (RN); level-1 pre-scaled by 2^12 before conversion
        half8 A0, A1;
        #pragma unroll
        for (int e = 0; e < 8; ++e) {
            const float v = h[e];
            const _Float16 q0 = (_Float16)v;
            A0[e] = q0;
            A1[e] = (_Float16)((v - (float)q0) * LVL_SCALE);
        }
        *(half8*)&s_a[w][0][l][0] = A0;
        *(half8*)&s_a[w][1][l][0] = A1;

        __syncthreads();   // B1: h1 fragments visible (4-wave domain)

        // ---- phase B: layer-2 via swapped fp16 MFMA, 3 terms, 2 jtiles ----
        f32x4 aA[2], aB[2], aC[2];
        #pragma unroll
        for (int jt = 0; jt < 2; ++jt) {
            aA[jt] = f32x4{0,0,0,0}; aB[jt] = f32x4{0,0,0,0}; aC[jt] = f32x4{0,0,0,0};
        }
        #pragma unroll
        for (int kc = 0; kc < 4; ++kc) {
            const half8 x0 = *(const half8*)&s_a[kc][0][l][0];
            const half8 x1 = *(const half8*)&s_a[kc][1][l][0];
            #pragma unroll
            for (int jt = 0; jt < 2; ++jt) {
                aA[jt] = __builtin_amdgcn_mfma_f32_16x16x32_f16(W2T0[jt][kc], x0, aA[jt], 0, 0, 0);
                aB[jt] = __builtin_amdgcn_mfma_f32_16x16x32_f16(W2T1[jt][kc], x0, aB[jt], 0, 0, 0);
                aC[jt] = __builtin_amdgcn_mfma_f32_16x16x32_f16(W2T0[jt][kc], x1, aC[jt], 0, 0, 0);
            }
        }
        // heads: h2 = aA + (aB + aC)*2^-12 + b2  (undo level-1 scaling)
        float fsc = 0.0f, msc = 0.0f;
        #pragma unroll
        for (int jt = 0; jt < 2; ++jt) {
            #pragma unroll
            for (int r = 0; r < 4; ++r) {
                const float h2 = leaky(aA[jt][r] + (aB[jt][r] + aC[jt][r]) * LVL_UNSCALE
                                       + b2r[jt][r]);
                fsc += h2 * wfr[jt][r];
                msc += h2 * wmr[jt][r];
            }
        }
        // reduce over lq (xor16/32)
        fsc += __shfl_xor(fsc, 16); fsc += __shfl_xor(fsc, 32);
        msc += __shfl_xor(msc, 16); msc += __shfl_xor(msc, 32);
        if (l < 16) *(float2*)&s_part[lm][w * 2] = make_float2(fsc, msc);

        __syncthreads();   // B2: head partials visible

        // ---- phase C: dynamics, redundant on all lanes (own elem bm) ----
        {
            const f32x4 p0 = *(const f32x4*)&s_part[lm][0];
            const f32x4 p1 = *(const f32x4*)&s_part[lm][4];
            const float fsum = bfv + p0.x + p0.z + p1.x + p1.z;
            const float msum = bmv + p0.y + p0.w + p1.y + p1.w;

            const float f_sc = fminf(fmaxf(fsum, -20.0f), 20.0f);
            const float m_sc = fminf(fmaxf(msum, -20.0f), 20.0f);
            const float dsc = 5.0f * (f_sc - m_sc);
            const float ex  = __expf(-fabsf(dsc));
            const float inv = frcp(1.0f + ex);
            const float fatt = (dsc >= 0.0f) ? inv : ex * inv;
            const float matt = 1.0f - fatt;

            // shared IDM terms
            const float rr_ = ego_v_r * pinv_v0;
            const float rr2 = rr_ * rr_;
            const float base = pamax * (1.0f - rr2 * rr2);
            // follower branch
            const float dxf = fminf(fmaxf(ef_dx_r, 0.1f), 500.0f);
            const float gapf = ptg * ego_v_r + ego_v_r * ef_dv_r * pinv_gd;
            const float dgf = pjam + fmaxf(gapf, 0.0f);
            const float qf = dgf * frcp(dxf);
            const float efa = fminf(fmaxf(base - pamax * qf * qf, -6.0f), 6.0f);
            // merger branch
            const float dxm = fminf(fmaxf(em_dx_r, 0.1f), 500.0f);
            const float gapm = ptg * ego_v_r + ego_v_r * em_dv_r * pinv_gd;
            const float dgm = pjam + fmaxf(gapm, 0.0f);
            const float qm = dgm * frcp(dxm);
            const float ema = fminf(fmaxf(base - pamax * qm * qm, -6.0f), 6.0f);

            const float a2n = fatt * efa + matt * ema;

            const float delta = ego_v_r * 0.1f + 0.005f * a2n;
            disp_r  += delta;
            ego_x_r += delta;
            ego_v_r += a2n * 0.1f;
            ego_a_r  = a2n;

            if (tid < 16) {
                out_disp[bm * 51 + t + 1] = disp_r;
                out_act [bm * 50 + t]     = a2n;
                out_fat [bm * 50 + t]     = fatt;
                out_mat [bm * 50 + t]     = matt;
            }

            if (t + 1 < NT) {
                ef_dx_r = nf_fx - ego_x_r;
                em_dx_r = (nf_mx - ego_x_r) * nf_me + (1.0f - nf_me) * 100.0f;
                ef_dv_r = ego_v_r - nf_fv;
                em_dv_r = (ego_v_r - nf_mv) * nf_me;
                c_fa = nf_fa; c_fv = nf_fv;
                c_m0 = nf_m0; c_m1 = nf_m1; c_m2 = nf_m2;
            }
        }
        // no 3rd barrier: s_a rewrite (t+1) is fenced by B2;
        // s_part rewrite (t+1) is fenced by B1(t+1).
    }
}

extern "C" void kernel_launch(void* const* d_in, const int* in_sizes, int n_in,
                              void* d_out, int out_size, void* d_ws, size_t ws_size,
                              hipStream_t stream) {
    (void)in_sizes; (void)n_in; (void)d_ws; (void)ws_size; (void)out_size;
    const float* idm_params  = (const float*)d_in[0];
    const float* proj_latent = (const float*)d_in[1];
    const float* enc_h       = (const float*)d_in[2];
    const float* idm_s       = (const float*)d_in[3];
    const float* merger_cs   = (const float*)d_in[4];
    const float* scaler_mean = (const float*)d_in[5];
    const float* scaler_var  = (const float*)d_in[6];
    const float* W1          = (const float*)d_in[7];
    const float* b1          = (const float*)d_in[8];
    const float* W2          = (const float*)d_in[9];
    const float* b2          = (const float*)d_in[10];
    const float* Wf          = (const float*)d_in[11];
    const float* bfp         = (const float*)d_in[12];
    const float* Wm          = (const float*)d_in[13];
    const float* bmp         = (const float*)d_in[14];

    idm_rollout_kernel<<<dim3(NB / 16), dim3(256), 0, stream>>>(
        idm_params, proj_latent, enc_h, idm_s, merger_cs,
        scaler_mean, scaler_var, W1, b1, W2, b2, Wf, bfp, Wm, bmp,
        (float*)d_out);
}

// Round 19
// 132.791 us; speedup vs baseline: 3.9664x; 1.1802x over previous
//
#include <hip/hip_runtime.h>

#define NB 8192
#define NT 50

typedef _Float16 half8 __attribute__((ext_vector_type(8)));
typedef float f32x4 __attribute__((ext_vector_type(4)));

__device__ __forceinline__ float leaky(float x) { return x > 0.0f ? x : 0.3f * x; }
__device__ __forceinline__ float frcp(float x) { return __builtin_amdgcn_rcpf(x); }

#define LVL_SCALE   4096.0f
#define LVL_UNSCALE 0.000244140625f   // 2^-12

extern "C" __global__ __launch_bounds__(256, 2)
void idm_rollout_kernel(const float* __restrict__ idm_params,
                        const float* __restrict__ proj_latent,
                        const float* __restrict__ enc_h,
                        const float* __restrict__ idm_s,
                        const float* __restrict__ merger_cs,
                        const float* __restrict__ scaler_mean,
                        const float* __restrict__ scaler_var,
                        const float* __restrict__ W1,
                        const float* __restrict__ b1,
                        const float* __restrict__ W2,
                        const float* __restrict__ b2,
                        const float* __restrict__ Wf,
                        const float* __restrict__ bfp,
                        const float* __restrict__ Wm,
                        const float* __restrict__ bmp,
                        float* __restrict__ out)
{
    // h1 2-level fp16 fragments: [kchunk][lvl][lane][e]
    __shared__ __align__(16) _Float16 s_a[4][2][64][8];    // 8 KB
    // dynamic W1 rows 256..266 (env rows pre-scaled by inv_std)
    __shared__ __align__(16) float s_w1d[11][128];         // 5.5 KB
    // head partials
    __shared__ __align__(16) float s_part[16][12];         // 0.75 KB
    // staged exogenous trajectory (row t holds global row t+1)
    __shared__ __align__(16) float s_tA[50][16][8];        // 25.6 KB: fv,mv,fx,mx,fa,me,pad,pad
    __shared__ __align__(16) float s_tB[50][16][4];        // 12.8 KB: m0,m1,m2,pad
    // output buffer: [elem][0..50 disp | 51..100 act | 101..150 fat]
    __shared__ float s_out[16][151];                       // 9.7 KB

    const int tid = threadIdx.x;       // 0..255
    const int w   = tid >> 6;          // wave 0..3
    const int l   = tid & 63;
    const int lm  = l & 15;
    const int lq  = l >> 4;
    const int b0  = blockIdx.x * 16;
    const int bm  = b0 + lm;
    const int c0  = w * 32 + lq * 8;   // this lane's 8 layer-1 columns (= consumer slice kc=w)

    // ---- stage dynamic W1 rows; env rows scaled by inv_std ----
    for (int idx = tid; idx < 11 * 128; idx += 256) {
        const int r = idx >> 7, c = idx & 127;
        float wv_ = W1[(256 + r) * 128 + c];
        if (r < 8) wv_ *= 1.0f / sqrtf(scaler_var[r]);
        s_w1d[r][c] = wv_;
    }
    // ---- stage exogenous trajectory (rows 1..49 -> s_t*[0..48]) ----
    for (int idx = tid; idx < 16 * 49 * 6; idx += 256) {
        const int e  = idx / 294;            // 49*6
        const int r2 = idx - e * 294;
        const int tt = r2 / 6;
        const int s  = r2 - tt * 6;
        const int col = (s < 2) ? (s + 1) : ((s < 4) ? (s + 2) : (s + 8)); // 1,2,4,5,12,13
        s_tA[tt][e][s] = idm_s[(size_t)(b0 + e) * 714 + (tt + 1) * 14 + col];
    }
    for (int idx = tid; idx < 16 * 49 * 3; idx += 256) {
        const int e  = idx / 147;            // 49*3
        const int r2 = idx - e * 147;
        const int tt = r2 / 3;
        const int s  = r2 - tt * 3;
        s_tB[tt][e][s] = merger_cs[(size_t)(b0 + e) * 150 + (tt + 1) * 3 + s];
    }
    if (tid < 16) s_out[tid][0] = 0.0f;

    // ---- W2^T A-frags for 2 jtiles, 2-level fp16 in registers ----
    half8 W2T0[2][4], W2T1[2][4];
    #pragma unroll
    for (int jt = 0; jt < 2; ++jt) {
        const int jtg = 2 * w + jt;
        #pragma unroll
        for (int kc = 0; kc < 4; ++kc) {
            #pragma unroll
            for (int e = 0; e < 8; ++e) {
                const int k = kc * 32 + lq * 8 + e;
                const float v = W2[k * 128 + jtg * 16 + lm];
                const _Float16 q0 = (_Float16)v;
                const float r1 = (v - (float)q0) * LVL_SCALE;
                W2T0[jt][kc][e] = q0;
                W2T1[jt][kc][e] = (_Float16)r1;
            }
        }
    }

    // ---- head constants ----
    f32x4 b2r[2], wfr[2], wmr[2];
    #pragma unroll
    for (int jt = 0; jt < 2; ++jt) {
        const int cb = (2 * w + jt) * 16 + lq * 4;
        b2r[jt] = *(const f32x4*)&b2[cb];
        wfr[jt] = *(const f32x4*)&Wf[cb];
        wmr[jt] = *(const f32x4*)&Wm[cb];
    }
    const float bfv = bfp[0];
    const float bmv = bmp[0];

    __syncthreads();   // staging complete (s_w1d, s_tA/B, s_out)

    // ---- hpre for (elem lm, cols c0..c0+7) ----
    f32x4 hpA = *(const f32x4*)&b1[c0];
    f32x4 hpB = *(const f32x4*)&b1[c0 + 4];
    {
        const float* xl0 = proj_latent + (size_t)bm * 128;
        const float* xl1 = enc_h + (size_t)bm * 128;
        #pragma unroll 2
        for (int r0 = 0; r0 < 128; r0 += 4) {
            const f32x4 x = *(const f32x4*)&xl0[r0];
            #pragma unroll
            for (int j = 0; j < 4; ++j) {
                hpA += x[j] * *(const f32x4*)&W1[(r0 + j) * 128 + c0];
                hpB += x[j] * *(const f32x4*)&W1[(r0 + j) * 128 + c0 + 4];
            }
        }
        #pragma unroll 2
        for (int r0 = 0; r0 < 128; r0 += 4) {
            const f32x4 x = *(const f32x4*)&xl1[r0];
            #pragma unroll
            for (int j = 0; j < 4; ++j) {
                hpA += x[j] * *(const f32x4*)&W1[(128 + r0 + j) * 128 + c0];
                hpB += x[j] * *(const f32x4*)&W1[(128 + r0 + j) * 128 + c0 + 4];
            }
        }
        #pragma unroll
        for (int rr = 0; rr < 8; ++rr) {
            const float c = scaler_mean[rr];
            hpA -= c * *(const f32x4*)&s_w1d[rr][c0];
            hpB -= c * *(const f32x4*)&s_w1d[rr][c0 + 4];
        }
    }

    // ---- per-lane dynamics state for elem bm (redundant x16) ----
    float ego_v_r, ego_a_r, ego_x_r, disp_r;
    float ef_dv_r, ef_dx_r, em_dv_r, em_dx_r;
    float c_fa, c_fv, c_m0, c_m1, c_m2;
    {
        const float* sr = idm_s + (size_t)bm * 714;
        const float* mr = merger_cs + (size_t)bm * 150;
        ego_v_r = sr[0]; ego_a_r = sr[11]; ego_x_r = sr[3]; disp_r = 0.0f;
        const float fv0 = sr[1], mv0 = sr[2], fx0 = sr[4], mx0 = sr[5];
        c_fa = sr[12];
        const float me0 = sr[13];
        c_fv = fv0;
        ef_dx_r = fx0 - ego_x_r;
        em_dx_r = (mx0 - ego_x_r) * me0 + (1.0f - me0) * 100.0f;
        ef_dv_r = ego_v_r - fv0;
        em_dv_r = (ego_v_r - mv0) * me0;
        c_m0 = mr[0]; c_m1 = mr[1]; c_m2 = mr[2];
    }
    const float ptg    = idm_params[bm * 5 + 1];
    const float pjam   = idm_params[bm * 5 + 2];
    const float pamax  = idm_params[bm * 5 + 3];
    const float pinv_v0 = 1.0f / idm_params[bm * 5 + 0];
    const float pinv_gd = 1.0f / (2.0f * sqrtf(pamax * idm_params[bm * 5 + 4]));

    for (int t = 0; t < NT; ++t) {
        // ---- phase A: layer-1 via VALU (8 cols, 11 dyn rows from LDS) ----
        float ev[11];
        ev[0] = ego_a_r; ev[1] = c_fa;    ev[2] = ego_v_r; ev[3] = c_fv;
        ev[4] = ef_dv_r; ev[5] = ef_dx_r; ev[6] = em_dv_r; ev[7] = em_dx_r;
        ev[8] = c_m0;    ev[9] = c_m1;    ev[10] = c_m2;
        f32x4 hqA = hpA, hqB = hpB;
        #pragma unroll
        for (int r = 0; r < 11; ++r) {
            hqA += ev[r] * *(const f32x4*)&s_w1d[r][c0];
            hqB += ev[r] * *(const f32x4*)&s_w1d[r][c0 + 4];
        }
        float h[8];
        h[0] = leaky(hqA.x); h[1] = leaky(hqA.y); h[2] = leaky(hqA.z); h[3] = leaky(hqA.w);
        h[4] = leaky(hqB.x); h[5] = leaky(hqB.y); h[6] = leaky(hqB.z); h[7] = leaky(hqB.w);

        // 2-level fp16 split (RN); level-1 pre-scaled by 2^12
        half8 A0, A1;
        #pragma unroll
        for (int e = 0; e < 8; ++e) {
            const float v = h[e];
            const _Float16 q0 = (_Float16)v;
            A0[e] = q0;
            A1[e] = (_Float16)((v - (float)q0) * LVL_SCALE);
        }
        *(half8*)&s_a[w][0][l][0] = A0;
        *(half8*)&s_a[w][1][l][0] = A1;

        __syncthreads();   // B1 (lgkm-only drain now)

        // ---- staged next-step scalars (LDS; latency hides under MFMAs) ----
        const f32x4  ta = *(const f32x4*)&s_tA[t][lm][0];   // fv,mv,fx,mx
        const float2 tb = *(const float2*)&s_tA[t][lm][4];  // fa,me
        const f32x4  tc = *(const f32x4*)&s_tB[t][lm][0];   // m0,m1,m2

        // ---- phase B: layer-2 via swapped fp16 MFMA, 3 terms, 2 jtiles ----
        f32x4 aA[2], aB[2], aC[2];
        #pragma unroll
        for (int jt = 0; jt < 2; ++jt) {
            aA[jt] = f32x4{0,0,0,0}; aB[jt] = f32x4{0,0,0,0}; aC[jt] = f32x4{0,0,0,0};
        }
        #pragma unroll
        for (int kc = 0; kc < 4; ++kc) {
            const half8 x0 = *(const half8*)&s_a[kc][0][l][0];
            const half8 x1 = *(const half8*)&s_a[kc][1][l][0];
            #pragma unroll
            for (int jt = 0; jt < 2; ++jt) {
                aA[jt] = __builtin_amdgcn_mfma_f32_16x16x32_f16(W2T0[jt][kc], x0, aA[jt], 0, 0, 0);
                aB[jt] = __builtin_amdgcn_mfma_f32_16x16x32_f16(W2T1[jt][kc], x0, aB[jt], 0, 0, 0);
                aC[jt] = __builtin_amdgcn_mfma_f32_16x16x32_f16(W2T0[jt][kc], x1, aC[jt], 0, 0, 0);
            }
        }
        float fsc = 0.0f, msc = 0.0f;
        #pragma unroll
        for (int jt = 0; jt < 2; ++jt) {
            #pragma unroll
            for (int r = 0; r < 4; ++r) {
                const float h2 = leaky(aA[jt][r] + (aB[jt][r] + aC[jt][r]) * LVL_UNSCALE
                                       + b2r[jt][r]);
                fsc += h2 * wfr[jt][r];
                msc += h2 * wmr[jt][r];
            }
        }
        fsc += __shfl_xor(fsc, 16); fsc += __shfl_xor(fsc, 32);
        msc += __shfl_xor(msc, 16); msc += __shfl_xor(msc, 32);
        if (l < 16) *(float2*)&s_part[lm][w * 2] = make_float2(fsc, msc);

        __syncthreads();   // B2 (lgkm-only drain)

        // ---- phase C: dynamics, redundant on all lanes (own elem bm) ----
        {
            const f32x4 p0 = *(const f32x4*)&s_part[lm][0];
            const f32x4 p1 = *(const f32x4*)&s_part[lm][4];
            const float fsum = bfv + p0.x + p0.z + p1.x + p1.z;
            const float msum = bmv + p0.y + p0.w + p1.y + p1.w;

            const float f_sc = fminf(fmaxf(fsum, -20.0f), 20.0f);
            const float m_sc = fminf(fmaxf(msum, -20.0f), 20.0f);
            const float dsc = 5.0f * (f_sc - m_sc);
            const float ex  = __expf(-fabsf(dsc));
            const float inv = frcp(1.0f + ex);
            const float fatt = (dsc >= 0.0f) ? inv : ex * inv;
            const float matt = 1.0f - fatt;

            const float rr_ = ego_v_r * pinv_v0;
            const float rr2 = rr_ * rr_;
            const float base = pamax * (1.0f - rr2 * rr2);
            const float dxf = fminf(fmaxf(ef_dx_r, 0.1f), 500.0f);
            const float gapf = ptg * ego_v_r + ego_v_r * ef_dv_r * pinv_gd;
            const float dgf = pjam + fmaxf(gapf, 0.0f);
            const float qf = dgf * frcp(dxf);
            const float efa = fminf(fmaxf(base - pamax * qf * qf, -6.0f), 6.0f);
            const float dxm = fminf(fmaxf(em_dx_r, 0.1f), 500.0f);
            const float gapm = ptg * ego_v_r + ego_v_r * em_dv_r * pinv_gd;
            const float dgm = pjam + fmaxf(gapm, 0.0f);
            const float qm = dgm * frcp(dxm);
            const float ema = fminf(fmaxf(base - pamax * qm * qm, -6.0f), 6.0f);

            const float a2n = fatt * efa + matt * ema;

            const float delta = ego_v_r * 0.1f + 0.005f * a2n;
            disp_r  += delta;
            ego_x_r += delta;
            ego_v_r += a2n * 0.1f;
            ego_a_r  = a2n;

            if (tid < 16) {
                s_out[lm][t + 1]   = disp_r;
                s_out[lm][51 + t]  = a2n;
                s_out[lm][101 + t] = fatt;
            }

            if (t + 1 < NT) {
                ef_dx_r = ta.z - ego_x_r;                               // fx
                em_dx_r = (ta.w - ego_x_r) * tb.y + (1.0f - tb.y) * 100.0f; // mx, me
                ef_dv_r = ego_v_r - ta.x;                               // fv
                em_dv_r = (ego_v_r - ta.y) * tb.y;                      // mv
                c_fa = tb.x; c_fv = ta.x;
                c_m0 = tc.x; c_m1 = tc.y; c_m2 = tc.z;
            }
        }
        // no 3rd barrier: s_a rewrite (t+1) is fenced by B2;
        // s_part rewrite (t+1) is fenced by B1(t+1).
    }

    // ---- flush outputs (coalesced, once) ----
    __syncthreads();
    float* out_disp = out;
    float* out_act  = out + NB * 51;
    float* out_fat  = out + NB * (51 + 50);
    float* out_mat  = out + NB * (51 + 100);
    for (int idx = tid; idx < 16 * 51; idx += 256)
        out_disp[b0 * 51 + idx] = s_out[idx / 51][idx % 51];
    for (int idx = tid; idx < 16 * 50; idx += 256) {
        const int e = idx / 50, t = idx % 50;
        out_act[b0 * 50 + idx] = s_out[e][51 + t];
        const float f = s_out[e][101 + t];
        out_fat[b0 * 50 + idx] = f;
        out_mat[b0 * 50 + idx] = 1.0f - f;
    }
}

extern "C" void kernel_launch(void* const* d_in, const int* in_sizes, int n_in,
                              void* d_out, int out_size, void* d_ws, size_t ws_size,
                              hipStream_t stream) {
    (void)in_sizes; (void)n_in; (void)d_ws; (void)ws_size; (void)out_size;
    const float* idm_params  = (const float*)d_in[0];
    const float* proj_latent = (const float*)d_in[1];
    const float* enc_h       = (const float*)d_in[2];
    const float* idm_s       = (const float*)d_in[3];
    const float* merger_cs   = (const float*)d_in[4];
    const float* scaler_mean = (const float*)d_in[5];
    const float* scaler_var  = (const float*)d_in[6];
    const float* W1          = (const float*)d_in[7];
    const float* b1          = (const float*)d_in[8];
    const float* W2          = (const float*)d_in[9];
    const float* b2          = (const float*)d_in[10];
    const float* Wf          = (const float*)d_in[11];
    const float* bfp         = (const float*)d_in[12];
    const float* Wm          = (const float*)d_in[13];
    const float* bmp         = (const float*)d_in[14];

    idm_rollout_kernel<<<dim3(NB / 16), dim3(256), 0, stream>>>(
        idm_params, proj_latent, enc_h, idm_s, merger_cs,
        scaler_mean, scaler_var, W1, b1, W2, b2, Wf, bfp, Wm, bmp,
        (float*)d_out);
}

// Round 20
// 132.519 us; speedup vs baseline: 3.9745x; 1.0021x over previous
//
#include <hip/hip_runtime.h>

#define NB 8192
#define NT 50

typedef _Float16 half8 __attribute__((ext_vector_type(8)));
typedef float f32x4 __attribute__((ext_vector_type(4)));

__device__ __forceinline__ float leaky(float x) { return x > 0.0f ? x : 0.3f * x; }
__device__ __forceinline__ float frcp(float x) { return __builtin_amdgcn_rcpf(x); }

#define LVL_SCALE   4096.0f
#define LVL_UNSCALE 0.000244140625f   // 2^-12

extern "C" __global__ __launch_bounds__(256, 2)
void idm_rollout_kernel(const float* __restrict__ idm_params,
                        const float* __restrict__ proj_latent,
                        const float* __restrict__ enc_h,
                        const float* __restrict__ idm_s,
                        const float* __restrict__ merger_cs,
                        const float* __restrict__ scaler_mean,
                        const float* __restrict__ scaler_var,
                        const float* __restrict__ W1,
                        const float* __restrict__ b1,
                        const float* __restrict__ W2,
                        const float* __restrict__ b2,
                        const float* __restrict__ Wf,
                        const float* __restrict__ bfp,
                        const float* __restrict__ Wm,
                        const float* __restrict__ bmp,
                        float* __restrict__ out)
{
    // h1 2-level fp16 fragments: [kchunk][lvl][lane][e]
    __shared__ __align__(16) _Float16 s_a[4][2][64][8];    // 8 KB
    // dynamic W1 rows 256..266 (env rows pre-scaled by inv_std)
    __shared__ __align__(16) float s_w1d[11][128];         // 5.5 KB
    // head partials
    __shared__ __align__(16) float s_part[16][12];         // 0.75 KB
    // staged exogenous trajectory, row t holds global row t+1.
    // slots 0..5: fv,mv,fx,mx,fa,me ; slots 8..10: m0,m1,m2.
    // stride 48B -> start banks 12*lm mod 32, max 2-way aliasing (free).
    __shared__ __align__(16) float s_t[50][16][12];        // 38.4 KB
    // output buffer: [elem][0..50 disp | 51..100 act | 101..150 fat]
    __shared__ float s_out[16][151];                       // 9.7 KB

    const int tid = threadIdx.x;       // 0..255
    const int w   = tid >> 6;          // wave 0..3
    const int l   = tid & 63;
    const int lm  = l & 15;
    const int lq  = l >> 4;
    const int b0  = blockIdx.x * 16;
    const int bm  = b0 + lm;
    const int c0  = w * 32 + lq * 8;   // this lane's 8 layer-1 columns (= consumer slice kc=w)

    // ---- stage dynamic W1 rows; env rows scaled by inv_std ----
    for (int idx = tid; idx < 11 * 128; idx += 256) {
        const int r = idx >> 7, c = idx & 127;
        float wv_ = W1[(256 + r) * 128 + c];
        if (r < 8) wv_ *= 1.0f / sqrtf(scaler_var[r]);
        s_w1d[r][c] = wv_;
    }
    // ---- stage exogenous trajectory (rows 1..49 -> s_t[0..48]) ----
    for (int idx = tid; idx < 16 * 49 * 6; idx += 256) {
        const int e  = idx / 294;            // 49*6
        const int r2 = idx - e * 294;
        const int tt = r2 / 6;
        const int s  = r2 - tt * 6;
        const int col = (s < 2) ? (s + 1) : ((s < 4) ? (s + 2) : (s + 8)); // 1,2,4,5,12,13
        s_t[tt][e][s] = idm_s[(size_t)(b0 + e) * 714 + (tt + 1) * 14 + col];
    }
    for (int idx = tid; idx < 16 * 49 * 3; idx += 256) {
        const int e  = idx / 147;            // 49*3
        const int r2 = idx - e * 147;
        const int tt = r2 / 3;
        const int s  = r2 - tt * 3;
        s_t[tt][e][8 + s] = merger_cs[(size_t)(b0 + e) * 150 + (tt + 1) * 3 + s];
    }
    if (tid < 16) s_out[tid][0] = 0.0f;

    // ---- W2^T A-frags for 2 jtiles, 2-level fp16 in registers ----
    half8 W2T0[2][4], W2T1[2][4];
    #pragma unroll
    for (int jt = 0; jt < 2; ++jt) {
        const int jtg = 2 * w + jt;
        #pragma unroll
        for (int kc = 0; kc < 4; ++kc) {
            #pragma unroll
            for (int e = 0; e < 8; ++e) {
                const int k = kc * 32 + lq * 8 + e;
                const float v = W2[k * 128 + jtg * 16 + lm];
                const _Float16 q0 = (_Float16)v;
                const float r1 = (v - (float)q0) * LVL_SCALE;
                W2T0[jt][kc][e] = q0;
                W2T1[jt][kc][e] = (_Float16)r1;
            }
        }
    }

    // ---- head constants ----
    f32x4 b2r[2], wfr[2], wmr[2];
    #pragma unroll
    for (int jt = 0; jt < 2; ++jt) {
        const int cb = (2 * w + jt) * 16 + lq * 4;
        b2r[jt] = *(const f32x4*)&b2[cb];
        wfr[jt] = *(const f32x4*)&Wf[cb];
        wmr[jt] = *(const f32x4*)&Wm[cb];
    }
    const float bfv = bfp[0];
    const float bmv = bmp[0];

    __syncthreads();   // staging complete (s_w1d, s_t, s_out)

    // ---- hpre for (elem lm, cols c0..c0+7) ----
    f32x4 hpA = *(const f32x4*)&b1[c0];
    f32x4 hpB = *(const f32x4*)&b1[c0 + 4];
    {
        const float* xl0 = proj_latent + (size_t)bm * 128;
        const float* xl1 = enc_h + (size_t)bm * 128;
        #pragma unroll 2
        for (int r0 = 0; r0 < 128; r0 += 4) {
            const f32x4 x = *(const f32x4*)&xl0[r0];
            #pragma unroll
            for (int j = 0; j < 4; ++j) {
                hpA += x[j] * *(const f32x4*)&W1[(r0 + j) * 128 + c0];
                hpB += x[j] * *(const f32x4*)&W1[(r0 + j) * 128 + c0 + 4];
            }
        }
        #pragma unroll 2
        for (int r0 = 0; r0 < 128; r0 += 4) {
            const f32x4 x = *(const f32x4*)&xl1[r0];
            #pragma unroll
            for (int j = 0; j < 4; ++j) {
                hpA += x[j] * *(const f32x4*)&W1[(128 + r0 + j) * 128 + c0];
                hpB += x[j] * *(const f32x4*)&W1[(128 + r0 + j) * 128 + c0 + 4];
            }
        }
        #pragma unroll
        for (int rr = 0; rr < 8; ++rr) {
            const float c = scaler_mean[rr];
            hpA -= c * *(const f32x4*)&s_w1d[rr][c0];
            hpB -= c * *(const f32x4*)&s_w1d[rr][c0 + 4];
        }
    }

    // ---- per-lane dynamics state for elem bm (redundant x16) ----
    float ego_v_r, ego_a_r, ego_x_r, disp_r;
    float ef_dv_r, ef_dx_r, em_dv_r, em_dx_r;
    float c_fa, c_fv, c_m0, c_m1, c_m2;
    {
        const float* sr = idm_s + (size_t)bm * 714;
        const float* mr = merger_cs + (size_t)bm * 150;
        ego_v_r = sr[0]; ego_a_r = sr[11]; ego_x_r = sr[3]; disp_r = 0.0f;
        const float fv0 = sr[1], mv0 = sr[2], fx0 = sr[4], mx0 = sr[5];
        c_fa = sr[12];
        const float me0 = sr[13];
        c_fv = fv0;
        ef_dx_r = fx0 - ego_x_r;
        em_dx_r = (mx0 - ego_x_r) * me0 + (1.0f - me0) * 100.0f;
        ef_dv_r = ego_v_r - fv0;
        em_dv_r = (ego_v_r - mv0) * me0;
        c_m0 = mr[0]; c_m1 = mr[1]; c_m2 = mr[2];
    }
    const float ptg    = idm_params[bm * 5 + 1];
    const float pjam   = idm_params[bm * 5 + 2];
    const float pamax  = idm_params[bm * 5 + 3];
    const float pinv_v0 = 1.0f / idm_params[bm * 5 + 0];
    const float pinv_gd = 1.0f / (2.0f * sqrtf(pamax * idm_params[bm * 5 + 4]));

    for (int t = 0; t < NT; ++t) {
        // ---- phase A: layer-1 via VALU (8 cols, 11 dyn rows from LDS) ----
        float ev[11];
        ev[0] = ego_a_r; ev[1] = c_fa;    ev[2] = ego_v_r; ev[3] = c_fv;
        ev[4] = ef_dv_r; ev[5] = ef_dx_r; ev[6] = em_dv_r; ev[7] = em_dx_r;
        ev[8] = c_m0;    ev[9] = c_m1;    ev[10] = c_m2;
        f32x4 hqA = hpA, hqB = hpB;
        #pragma unroll
        for (int r = 0; r < 11; ++r) {
            hqA += ev[r] * *(const f32x4*)&s_w1d[r][c0];
            hqB += ev[r] * *(const f32x4*)&s_w1d[r][c0 + 4];
        }
        float h[8];
        h[0] = leaky(hqA.x); h[1] = leaky(hqA.y); h[2] = leaky(hqA.z); h[3] = leaky(hqA.w);
        h[4] = leaky(hqB.x); h[5] = leaky(hqB.y); h[6] = leaky(hqB.z); h[7] = leaky(hqB.w);

        // 2-level fp16 split (RN); level-1 pre-scaled by 2^12
        half8 A0, A1;
        #pragma unroll
        for (int e = 0; e < 8; ++e) {
            const float v = h[e];
            const _Float16 q0 = (_Float16)v;
            A0[e] = q0;
            A1[e] = (_Float16)((v - (float)q0) * LVL_SCALE);
        }
        *(half8*)&s_a[w][0][l][0] = A0;
        *(half8*)&s_a[w][1][l][0] = A1;

        __syncthreads();   // B1 (lgkm-only drain)

        // ---- staged next-step scalars (LDS; latency hides under MFMAs) ----
        const f32x4  ta = *(const f32x4*)&s_t[t][lm][0];    // fv,mv,fx,mx
        const float2 tb = *(const float2*)&s_t[t][lm][4];   // fa,me
        const f32x4  tc = *(const f32x4*)&s_t[t][lm][8];    // m0,m1,m2

        // ---- phase B: layer-2 via swapped fp16 MFMA, 3 terms, 2 jtiles ----
        f32x4 aA[2], aB[2], aC[2];
        #pragma unroll
        for (int jt = 0; jt < 2; ++jt) {
            aA[jt] = f32x4{0,0,0,0}; aB[jt] = f32x4{0,0,0,0}; aC[jt] = f32x4{0,0,0,0};
        }
        #pragma unroll
        for (int kc = 0; kc < 4; ++kc) {
            const half8 x0 = *(const half8*)&s_a[kc][0][l][0];
            const half8 x1 = *(const half8*)&s_a[kc][1][l][0];
            #pragma unroll
            for (int jt = 0; jt < 2; ++jt) {
                aA[jt] = __builtin_amdgcn_mfma_f32_16x16x32_f16(W2T0[jt][kc], x0, aA[jt], 0, 0, 0);
                aB[jt] = __builtin_amdgcn_mfma_f32_16x16x32_f16(W2T1[jt][kc], x0, aB[jt], 0, 0, 0);
                aC[jt] = __builtin_amdgcn_mfma_f32_16x16x32_f16(W2T0[jt][kc], x1, aC[jt], 0, 0, 0);
            }
        }
        float fsc = 0.0f, msc = 0.0f;
        #pragma unroll
        for (int jt = 0; jt < 2; ++jt) {
            #pragma unroll
            for (int r = 0; r < 4; ++r) {
                const float h2 = leaky(aA[jt][r] + (aB[jt][r] + aC[jt][r]) * LVL_UNSCALE
                                       + b2r[jt][r]);
                fsc += h2 * wfr[jt][r];
                msc += h2 * wmr[jt][r];
            }
        }
        fsc += __shfl_xor(fsc, 16); fsc += __shfl_xor(fsc, 32);
        msc += __shfl_xor(msc, 16); msc += __shfl_xor(msc, 32);
        if (l < 16) *(float2*)&s_part[lm][w * 2] = make_float2(fsc, msc);

        __syncthreads();   // B2 (lgkm-only drain)

        // ---- phase C: dynamics, redundant on all lanes (own elem bm) ----
        {
            const f32x4 p0 = *(const f32x4*)&s_part[lm][0];
            const f32x4 p1 = *(const f32x4*)&s_part[lm][4];
            const float fsum = bfv + p0.x + p0.z + p1.x + p1.z;
            const float msum = bmv + p0.y + p0.w + p1.y + p1.w;

            const float f_sc = fminf(fmaxf(fsum, -20.0f), 20.0f);
            const float m_sc = fminf(fmaxf(msum, -20.0f), 20.0f);
            const float dsc = 5.0f * (f_sc - m_sc);
            const float ex  = __expf(-fabsf(dsc));
            const float inv = frcp(1.0f + ex);
            const float fatt = (dsc >= 0.0f) ? inv : ex * inv;
            const float matt = 1.0f - fatt;

            const float rr_ = ego_v_r * pinv_v0;
            const float rr2 = rr_ * rr_;
            const float base = pamax * (1.0f - rr2 * rr2);
            const float dxf = fminf(fmaxf(ef_dx_r, 0.1f), 500.0f);
            const float gapf = ptg * ego_v_r + ego_v_r * ef_dv_r * pinv_gd;
            const float dgf = pjam + fmaxf(gapf, 0.0f);
            const float qf = dgf * frcp(dxf);
            const float efa = fminf(fmaxf(base - pamax * qf * qf, -6.0f), 6.0f);
            const float dxm = fminf(fmaxf(em_dx_r, 0.1f), 500.0f);
            const float gapm = ptg * ego_v_r + ego_v_r * em_dv_r * pinv_gd;
            const float dgm = pjam + fmaxf(gapm, 0.0f);
            const float qm = dgm * frcp(dxm);
            const float ema = fminf(fmaxf(base - pamax * qm * qm, -6.0f), 6.0f);

            const float a2n = fatt * efa + matt * ema;

            const float delta = ego_v_r * 0.1f + 0.005f * a2n;
            disp_r  += delta;
            ego_x_r += delta;
            ego_v_r += a2n * 0.1f;
            ego_a_r  = a2n;

            if (tid < 16) {
                s_out[lm][t + 1]   = disp_r;
                s_out[lm][51 + t]  = a2n;
                s_out[lm][101 + t] = fatt;
            }

            if (t + 1 < NT) {
                ef_dx_r = ta.z - ego_x_r;
                em_dx_r = (ta.w - ego_x_r) * tb.y + (1.0f - tb.y) * 100.0f;
                ef_dv_r = ego_v_r - ta.x;
                em_dv_r = (ego_v_r - ta.y) * tb.y;
                c_fa = tb.x; c_fv = ta.x;
                c_m0 = tc.x; c_m1 = tc.y; c_m2 = tc.z;
            }
        }
        // no 3rd barrier: s_a rewrite (t+1) is fenced by B2;
        // s_part rewrite (t+1) is fenced by B1(t+1).
    }

    // ---- flush outputs (coalesced, once) ----
    __syncthreads();
    float* out_disp = out;
    float* out_act  = out + NB * 51;
    float* out_fat  = out + NB * (51 + 50);
    float* out_mat  = out + NB * (51 + 100);
    for (int idx = tid; idx < 16 * 51; idx += 256)
        out_disp[b0 * 51 + idx] = s_out[idx / 51][idx % 51];
    for (int idx = tid; idx < 16 * 50; idx += 256) {
        const int e = idx / 50, t = idx % 50;
        out_act[b0 * 50 + idx] = s_out[e][51 + t];
        const float f = s_out[e][101 + t];
        out_fat[b0 * 50 + idx] = f;
        out_mat[b0 * 50 + idx] = 1.0f - f;
    }
}

extern "C" void kernel_launch(void* const* d_in, const int* in_sizes, int n_in,
                              void* d_out, int out_size, void* d_ws, size_t ws_size,
                              hipStream_t stream) {
    (void)in_sizes; (void)n_in; (void)d_ws; (void)ws_size; (void)out_size;
    const float* idm_params  = (const float*)d_in[0];
    const float* proj_latent = (const float*)d_in[1];
    const float* enc_h       = (const float*)d_in[2];
    const float* idm_s       = (const float*)d_in[3];
    const float* merger_cs   = (const float*)d_in[4];
    const float* scaler_mean = (const float*)d_in[5];
    const float* scaler_var  = (const float*)d_in[6];
    const float* W1          = (const float*)d_in[7];
    const float* b1          = (const float*)d_in[8];
    const float* W2          = (const float*)d_in[9];
    const float* b2          = (const float*)d_in[10];
    const float* Wf          = (const float*)d_in[11];
    const float* bfp         = (const float*)d_in[12];
    const float* Wm          = (const float*)d_in[13];
    const float* bmp         = (const float*)d_in[14];

    idm_rollout_kernel<<<dim3(NB / 16), dim3(256), 0, stream>>>(
        idm_params, proj_latent, enc_h, idm_s, merger_cs,
        scaler_mean, scaler_var, W1, b1, W2, b2, Wf, bfp, Wm, bmp,
        (float*)d_out);
}

// Round 21
// 132.023 us; speedup vs baseline: 3.9894x; 1.0038x over previous
//
#include <hip/hip_runtime.h>

#define NB 8192
#define NT 50

typedef _Float16 half8 __attribute__((ext_vector_type(8)));
typedef float f32x4 __attribute__((ext_vector_type(4)));

__device__ __forceinline__ float leaky(float x) { return x > 0.0f ? x : 0.3f * x; }
__device__ __forceinline__ float frcp(float x) { return __builtin_amdgcn_rcpf(x); }

#define LVL_SCALE   4096.0f
#define LVL_UNSCALE 0.000244140625f   // 2^-12

extern "C" __global__ __launch_bounds__(256, 2)
void idm_rollout_kernel(const float* __restrict__ idm_params,
                        const float* __restrict__ proj_latent,
                        const float* __restrict__ enc_h,
                        const float* __restrict__ idm_s,
                        const float* __restrict__ merger_cs,
                        const float* __restrict__ scaler_mean,
                        const float* __restrict__ scaler_var,
                        const float* __restrict__ W1,
                        const float* __restrict__ b1,
                        const float* __restrict__ W2,
                        const float* __restrict__ b2,
                        const float* __restrict__ Wf,
                        const float* __restrict__ bfp,
                        const float* __restrict__ Wm,
                        const float* __restrict__ bmp,
                        float* __restrict__ out)
{
    // h1 2-level fp16 fragments: [kchunk][lvl][lane][e]
    __shared__ __align__(16) _Float16 s_a[4][2][64][8];    // 8 KB
    // dynamic W1 rows 256..266 (env rows pre-scaled by inv_std)
    __shared__ __align__(16) float s_w1d[11][128];         // 5.5 KB
    // head partials
    __shared__ __align__(16) float s_part[16][12];         // 0.75 KB
    // staged exogenous trajectory, row t holds global row t+1.
    __shared__ __align__(16) float s_t[50][16][12];        // 38.4 KB
    // output buffer: [elem][0..50 disp | 51..100 act | 101..150 fat]
    __shared__ float s_out[16][151];                       // 9.7 KB

    const int tid = threadIdx.x;       // 0..255
    const int w   = tid >> 6;          // wave 0..3
    const int l   = tid & 63;
    const int lm  = l & 15;
    const int lq  = l >> 4;
    const int b0  = blockIdx.x * 16;
    const int bm  = b0 + lm;
    const int c0  = w * 32 + lq * 8;   // this lane's 8 layer-1 columns (= consumer slice kc=w)

    // ---- stage dynamic W1 rows; env rows scaled by inv_std ----
    for (int idx = tid; idx < 11 * 128; idx += 256) {
        const int r = idx >> 7, c = idx & 127;
        float wv_ = W1[(256 + r) * 128 + c];
        if (r < 8) wv_ *= 1.0f / sqrtf(scaler_var[r]);
        s_w1d[r][c] = wv_;
    }
    // ---- stage exogenous trajectory (rows 1..49 -> s_t[0..48]) ----
    for (int idx = tid; idx < 16 * 49 * 6; idx += 256) {
        const int e  = idx / 294;            // 49*6
        const int r2 = idx - e * 294;
        const int tt = r2 / 6;
        const int s  = r2 - tt * 6;
        const int col = (s < 2) ? (s + 1) : ((s < 4) ? (s + 2) : (s + 8)); // 1,2,4,5,12,13
        s_t[tt][e][s] = idm_s[(size_t)(b0 + e) * 714 + (tt + 1) * 14 + col];
    }
    for (int idx = tid; idx < 16 * 49 * 3; idx += 256) {
        const int e  = idx / 147;            // 49*3
        const int r2 = idx - e * 147;
        const int tt = r2 / 3;
        const int s  = r2 - tt * 3;
        s_t[tt][e][8 + s] = merger_cs[(size_t)(b0 + e) * 150 + (tt + 1) * 3 + s];
    }
    if (tid < 16) s_out[tid][0] = 0.0f;

    // ---- W2^T A-frags for 2 jtiles, 2-level fp16 in registers ----
    half8 W2T0[2][4], W2T1[2][4];
    #pragma unroll
    for (int jt = 0; jt < 2; ++jt) {
        const int jtg = 2 * w + jt;
        #pragma unroll
        for (int kc = 0; kc < 4; ++kc) {
            #pragma unroll
            for (int e = 0; e < 8; ++e) {
                const int k = kc * 32 + lq * 8 + e;
                const float v = W2[k * 128 + jtg * 16 + lm];
                const _Float16 q0 = (_Float16)v;
                const float r1 = (v - (float)q0) * LVL_SCALE;
                W2T0[jt][kc][e] = q0;
                W2T1[jt][kc][e] = (_Float16)r1;
            }
        }
    }

    // ---- head constants ----
    f32x4 b2r[2], wfr[2], wmr[2];
    #pragma unroll
    for (int jt = 0; jt < 2; ++jt) {
        const int cb = (2 * w + jt) * 16 + lq * 4;
        b2r[jt] = *(const f32x4*)&b2[cb];
        wfr[jt] = *(const f32x4*)&Wf[cb];
        wmr[jt] = *(const f32x4*)&Wm[cb];
    }
    const float bfv = bfp[0];
    const float bmv = bmp[0];

    __syncthreads();   // staging complete (s_w1d, s_t, s_out)

    // ---- hpre for (elem lm, cols c0..c0+7) ----
    f32x4 hpA = *(const f32x4*)&b1[c0];
    f32x4 hpB = *(const f32x4*)&b1[c0 + 4];
    {
        const float* xl0 = proj_latent + (size_t)bm * 128;
        const float* xl1 = enc_h + (size_t)bm * 128;
        #pragma unroll 2
        for (int r0 = 0; r0 < 128; r0 += 4) {
            const f32x4 x = *(const f32x4*)&xl0[r0];
            #pragma unroll
            for (int j = 0; j < 4; ++j) {
                hpA += x[j] * *(const f32x4*)&W1[(r0 + j) * 128 + c0];
                hpB += x[j] * *(const f32x4*)&W1[(r0 + j) * 128 + c0 + 4];
            }
        }
        #pragma unroll 2
        for (int r0 = 0; r0 < 128; r0 += 4) {
            const f32x4 x = *(const f32x4*)&xl1[r0];
            #pragma unroll
            for (int j = 0; j < 4; ++j) {
                hpA += x[j] * *(const f32x4*)&W1[(128 + r0 + j) * 128 + c0];
                hpB += x[j] * *(const f32x4*)&W1[(128 + r0 + j) * 128 + c0 + 4];
            }
        }
        #pragma unroll
        for (int rr = 0; rr < 8; ++rr) {
            const float c = scaler_mean[rr];
            hpA -= c * *(const f32x4*)&s_w1d[rr][c0];
            hpB -= c * *(const f32x4*)&s_w1d[rr][c0 + 4];
        }
    }

    // ---- per-lane dynamics state for elem bm (redundant x16) ----
    float ego_v_r, ego_a_r, ego_x_r, disp_r;
    float ef_dv_r, ef_dx_r, em_dv_r, em_dx_r;
    float c_fa, c_fv, c_m0, c_m1, c_m2;
    {
        const float* sr = idm_s + (size_t)bm * 714;
        const float* mr = merger_cs + (size_t)bm * 150;
        ego_v_r = sr[0]; ego_a_r = sr[11]; ego_x_r = sr[3]; disp_r = 0.0f;
        const float fv0 = sr[1], mv0 = sr[2], fx0 = sr[4], mx0 = sr[5];
        c_fa = sr[12];
        const float me0 = sr[13];
        c_fv = fv0;
        ef_dx_r = fx0 - ego_x_r;
        em_dx_r = (mx0 - ego_x_r) * me0 + (1.0f - me0) * 100.0f;
        ef_dv_r = ego_v_r - fv0;
        em_dv_r = (ego_v_r - mv0) * me0;
        c_m0 = mr[0]; c_m1 = mr[1]; c_m2 = mr[2];
    }
    const float ptg    = idm_params[bm * 5 + 1];
    const float pjam   = idm_params[bm * 5 + 2];
    const float pamax  = idm_params[bm * 5 + 3];
    const float pinv_v0 = 1.0f / idm_params[bm * 5 + 0];
    const float pinv_gd = 1.0f / (2.0f * sqrtf(pamax * idm_params[bm * 5 + 4]));

    for (int t = 0; t < NT; ++t) {
        // ---- staged next-step scalars: issue at top of step (s_t is static) ----
        const f32x4  ta = *(const f32x4*)&s_t[t][lm][0];    // fv,mv,fx,mx
        const float2 tb = *(const float2*)&s_t[t][lm][4];   // fa,me
        const f32x4  tc = *(const f32x4*)&s_t[t][lm][8];    // m0,m1,m2

        // ---- phase A: layer-1 via VALU (8 cols, 11 dyn rows from LDS) ----
        float ev[11];
        ev[0] = ego_a_r; ev[1] = c_fa;    ev[2] = ego_v_r; ev[3] = c_fv;
        ev[4] = ef_dv_r; ev[5] = ef_dx_r; ev[6] = em_dv_r; ev[7] = em_dx_r;
        ev[8] = c_m0;    ev[9] = c_m1;    ev[10] = c_m2;
        f32x4 hqA = hpA, hqB = hpB;
        #pragma unroll
        for (int r = 0; r < 11; ++r) {
            hqA += ev[r] * *(const f32x4*)&s_w1d[r][c0];
            hqB += ev[r] * *(const f32x4*)&s_w1d[r][c0 + 4];
        }
        float h[8];
        h[0] = leaky(hqA.x); h[1] = leaky(hqA.y); h[2] = leaky(hqA.z); h[3] = leaky(hqA.w);
        h[4] = leaky(hqB.x); h[5] = leaky(hqB.y); h[6] = leaky(hqB.z); h[7] = leaky(hqB.w);

        // 2-level fp16 split (RN); level-1 pre-scaled by 2^12
        half8 A0, A1;
        #pragma unroll
        for (int e = 0; e < 8; ++e) {
            const float v = h[e];
            const _Float16 q0 = (_Float16)v;
            A0[e] = q0;
            A1[e] = (_Float16)((v - (float)q0) * LVL_SCALE);
        }
        *(half8*)&s_a[w][0][l][0] = A0;
        *(half8*)&s_a[w][1][l][0] = A1;

        __syncthreads();   // B1 (lgkm-only drain)

        // ---- phase B: layer-2 via swapped fp16 MFMA, 3 terms, 2 jtiles ----
        // aA = main term; aBC = both 2^-12-scaled correction terms (merged chain)
        f32x4 aA[2], aBC[2];
        #pragma unroll
        for (int jt = 0; jt < 2; ++jt) {
            aA[jt] = f32x4{0,0,0,0}; aBC[jt] = f32x4{0,0,0,0};
        }
        __builtin_amdgcn_s_setprio(1);
        #pragma unroll
        for (int kc = 0; kc < 4; ++kc) {
            const half8 x0 = *(const half8*)&s_a[kc][0][l][0];
            const half8 x1 = *(const half8*)&s_a[kc][1][l][0];
            #pragma unroll
            for (int jt = 0; jt < 2; ++jt) {
                aA[jt]  = __builtin_amdgcn_mfma_f32_16x16x32_f16(W2T0[jt][kc], x0, aA[jt], 0, 0, 0);
                aBC[jt] = __builtin_amdgcn_mfma_f32_16x16x32_f16(W2T1[jt][kc], x0, aBC[jt], 0, 0, 0);
                aBC[jt] = __builtin_amdgcn_mfma_f32_16x16x32_f16(W2T0[jt][kc], x1, aBC[jt], 0, 0, 0);
            }
        }
        __builtin_amdgcn_s_setprio(0);
        float fsc = 0.0f, msc = 0.0f;
        #pragma unroll
        for (int jt = 0; jt < 2; ++jt) {
            #pragma unroll
            for (int r = 0; r < 4; ++r) {
                const float h2 = leaky(aA[jt][r] + aBC[jt][r] * LVL_UNSCALE + b2r[jt][r]);
                fsc += h2 * wfr[jt][r];
                msc += h2 * wmr[jt][r];
            }
        }
        fsc += __shfl_xor(fsc, 16); fsc += __shfl_xor(fsc, 32);
        msc += __shfl_xor(msc, 16); msc += __shfl_xor(msc, 32);
        if (l < 16) *(float2*)&s_part[lm][w * 2] = make_float2(fsc, msc);

        __syncthreads();   // B2 (lgkm-only drain)

        // ---- phase C: dynamics, redundant on all lanes (own elem bm) ----
        {
            const f32x4 p0 = *(const f32x4*)&s_part[lm][0];
            const f32x4 p1 = *(const f32x4*)&s_part[lm][4];
            const float fsum = bfv + p0.x + p0.z + p1.x + p1.z;
            const float msum = bmv + p0.y + p0.w + p1.y + p1.w;

            const float f_sc = fminf(fmaxf(fsum, -20.0f), 20.0f);
            const float m_sc = fminf(fmaxf(msum, -20.0f), 20.0f);
            const float dsc = 5.0f * (f_sc - m_sc);
            const float ex  = __expf(-fabsf(dsc));
            const float inv = frcp(1.0f + ex);
            const float fatt = (dsc >= 0.0f) ? inv : ex * inv;
            const float matt = 1.0f - fatt;

            const float rr_ = ego_v_r * pinv_v0;
            const float rr2 = rr_ * rr_;
            const float base = pamax * (1.0f - rr2 * rr2);
            const float dxf = fminf(fmaxf(ef_dx_r, 0.1f), 500.0f);
            const float gapf = ptg * ego_v_r + ego_v_r * ef_dv_r * pinv_gd;
            const float dgf = pjam + fmaxf(gapf, 0.0f);
            const float qf = dgf * frcp(dxf);
            const float efa = fminf(fmaxf(base - pamax * qf * qf, -6.0f), 6.0f);
            const float dxm = fminf(fmaxf(em_dx_r, 0.1f), 500.0f);
            const float gapm = ptg * ego_v_r + ego_v_r * em_dv_r * pinv_gd;
            const float dgm = pjam + fmaxf(gapm, 0.0f);
            const float qm = dgm * frcp(dxm);
            const float ema = fminf(fmaxf(base - pamax * qm * qm, -6.0f), 6.0f);

            const float a2n = fatt * efa + matt * ema;

            const float delta = ego_v_r * 0.1f + 0.005f * a2n;
            disp_r  += delta;
            ego_x_r += delta;
            ego_v_r += a2n * 0.1f;
            ego_a_r  = a2n;

            if (tid < 16) {
                s_out[lm][t + 1]   = disp_r;
                s_out[lm][51 + t]  = a2n;
                s_out[lm][101 + t] = fatt;
            }

            if (t + 1 < NT) {
                ef_dx_r = ta.z - ego_x_r;
                em_dx_r = (ta.w - ego_x_r) * tb.y + (1.0f - tb.y) * 100.0f;
                ef_dv_r = ego_v_r - ta.x;
                em_dv_r = (ego_v_r - ta.y) * tb.y;
                c_fa = tb.x; c_fv = ta.x;
                c_m0 = tc.x; c_m1 = tc.y; c_m2 = tc.z;
            }
        }
        // no 3rd barrier: s_a rewrite (t+1) is fenced by B2;
        // s_part rewrite (t+1) is fenced by B1(t+1).
    }

    // ---- flush outputs (coalesced, once) ----
    __syncthreads();
    float* out_disp = out;
    float* out_act  = out + NB * 51;
    float* out_fat  = out + NB * (51 + 50);
    float* out_mat  = out + NB * (51 + 100);
    for (int idx = tid; idx < 16 * 51; idx += 256)
        out_disp[b0 * 51 + idx] = s_out[idx / 51][idx % 51];
    for (int idx = tid; idx < 16 * 50; idx += 256) {
        const int e = idx / 50, t = idx % 50;
        out_act[b0 * 50 + idx] = s_out[e][51 + t];
        const float f = s_out[e][101 + t];
        out_fat[b0 * 50 + idx] = f;
        out_mat[b0 * 50 + idx] = 1.0f - f;
    }
}

extern "C" void kernel_launch(void* const* d_in, const int* in_sizes, int n_in,
                              void* d_out, int out_size, void* d_ws, size_t ws_size,
                              hipStream_t stream) {
    (void)in_sizes; (void)n_in; (void)d_ws; (void)ws_size; (void)out_size;
    const float* idm_params  = (const float*)d_in[0];
    const float* proj_latent = (const float*)d_in[1];
    const float* enc_h       = (const float*)d_in[2];
    const float* idm_s       = (const float*)d_in[3];
    const float* merger_cs   = (const float*)d_in[4];
    const float* scaler_mean = (const float*)d_in[5];
    const float* scaler_var  = (const float*)d_in[6];
    const float* W1          = (const float*)d_in[7];
    const float* b1          = (const float*)d_in[8];
    const float* W2          = (const float*)d_in[9];
    const float* b2          = (const float*)d_in[10];
    const float* Wf          = (const float*)d_in[11];
    const float* bfp         = (const float*)d_in[12];
    const float* Wm          = (const float*)d_in[13];
    const float* bmp         = (const float*)d_in[14];

    idm_rollout_kernel<<<dim3(NB / 16), dim3(256), 0, stream>>>(
        idm_params, proj_latent, enc_h, idm_s, merger_cs,
        scaler_mean, scaler_var, W1, b1, W2, b2, Wf, bfp, Wm, bmp,
        (float*)d_out);
}